// Round 6
// baseline (981.099 us; speedup 1.0000x reference)
//
#include <hip/hip_runtime.h>
#include <hip/hip_bf16.h>
#include <stdint.h>

typedef __hip_bfloat16 bf16;
typedef __attribute__((ext_vector_type(8))) short short8;
typedef __attribute__((ext_vector_type(16))) float floatx16;
typedef __attribute__((address_space(3))) const unsigned short lu16;
typedef __attribute__((address_space(3))) const char lchar;

// ---------- helpers ----------
__device__ __forceinline__ unsigned short f2bu(float f) {
  bf16 b = __float2bfloat16(f);
  return *reinterpret_cast<unsigned short*>(&b);
}

__device__ __forceinline__ void stf(float* p, float v) { *p = v; }
__device__ __forceinline__ void stf(bf16* p, float v) { *p = __float2bfloat16(v); }

// vectorized 4-element loads -> f32 lanes (bf16 source: 8B/lane)
__device__ __forceinline__ void ld4(const bf16* p, float* o) {
  ushort4 v = *(const ushort4*)p;
  o[0] = __bfloat162float(*(bf16*)&v.x);
  o[1] = __bfloat162float(*(bf16*)&v.y);
  o[2] = __bfloat162float(*(bf16*)&v.z);
  o[3] = __bfloat162float(*(bf16*)&v.w);
}

// async global->LDS, 16B per lane; lds base wave-uniform, HW writes base + lane*16
__device__ __forceinline__ void gl_lds16(const bf16* g, bf16* l) {
  __builtin_amdgcn_global_load_lds((const __attribute__((address_space(1))) void*)g,
                                   (__attribute__((address_space(3))) void*)l,
                                   16, 0, 0);
}

// inline-asm ds_read_b128 with compile-time byte offset
template <int OFF>
__device__ __forceinline__ short8 ldsro(lu16* p) {
  short8 r;
  asm volatile("ds_read_b128 %0, %1 offset:%2" : "=v"(r) : "v"(p), "i"(OFF));
  return r;
}

#define BAR() __builtin_amdgcn_s_barrier()
#define WAITLG(n) do { asm volatile("s_waitcnt lgkmcnt(" #n ")" ::: "memory"); \
                       __builtin_amdgcn_sched_barrier(0); } while (0)
#define VMCNT(n) asm volatile("s_waitcnt vmcnt(" #n ")" ::: "memory")

// ---------- conversions ----------
__global__ void cvt_f32_bf16(const float* __restrict__ in, bf16* __restrict__ out, long n4) {
  long i = (long)blockIdx.x * blockDim.x + threadIdx.x;
  if (i >= n4) return;
  float4 v = ((const float4*)in)[i];
  ushort4 o;
  o.x = f2bu(v.x); o.y = f2bu(v.y); o.z = f2bu(v.z); o.w = f2bu(v.w);
  ((ushort4*)out)[i] = o;
}

// in: [R][Cc] f32 -> out: [Cc][R] bf16   (R, Cc multiples of 32)
__global__ void transpose_f32_to_bf16(const float* __restrict__ in, bf16* __restrict__ out,
                                      int R, int Cc) {
  __shared__ float tile[32][33];
  int tx = threadIdx.x & 31;
  int ty = threadIdx.x >> 5;  // 0..7
  int c0 = blockIdx.x * 32;
  int r0 = blockIdx.y * 32;
#pragma unroll
  for (int i = 0; i < 32; i += 8)
    tile[ty + i][tx] = in[(long)(r0 + ty + i) * Cc + c0 + tx];
  __syncthreads();
#pragma unroll
  for (int i = 0; i < 32; i += 8)
    out[(long)(c0 + ty + i) * R + r0 + tx] = __float2bfloat16(tile[tx][ty + i]);
}

// ---------- GEMM: C[M][N] = A[M][K] * BT[N][K]^T, bf16 in, OUT_T out ----------
// 256x256 tile, BK=64, 512 threads = 8 waves (2M x 4N), mfma_f32_32x32x16_bf16
// (4061 FLOP/cyc/CU ceiling vs 3378 for 16x16x32).  Wave tile 128x64 =
// 4 m-blocks x 2 n-blocks of 32x32, K split in 4 k16-groups (t=0..3).
// TWO phases per K-tile: Phase A reads A t0/t1 (8) + ALL B t0-3 (8) and runs
// 16 MFMA (t0,t1) under a staggered lgkm ladder ending at lgkmcnt(0); Phase B
// reads A t2/t3 (8) and runs 16 MFMA (t2,t3).  One barrier per phase; every
// wave hits lgkmcnt(0) before its barrier, so each staged region stays >=1
// barrier after its last reader (identical liveness to the verified 2-phase
// 16x16 schedule: A staged in phA -> other buf; B staged in phB -> this buf,
// whose B-region was last read in phA).  vmcnt(4) at phB end.
// LDS XOR swizzle: 16B slot s of row r at phys s ^ (r&7).  32x32 fragment
// reads: lane l reads row (l&31), logical slot 2t + (l>>5); since
// 2t+hi == 2t^hi, the per-t address is base ^ (t*32) -- swizzle-compatible.
// Per quarter-wave: 16 consecutive rows -> 8 phys slots x 2 lanes (conflict-
// free, same structure as the 16x16 version that measures 0 conflicts).
// Requires M%256==0, N%256==0, K%128==0, gridDim.x%8==0.
template <typename OUT_T>
__global__ __launch_bounds__(512, 2) void gemm256(const bf16* __restrict__ A,
                                                  const bf16* __restrict__ BT,
                                                  OUT_T* __restrict__ C,
                                                  int M, int N, int K) {
  __shared__ __align__(16) bf16 lds[2][2][256][64];  // [buf][A/B][row][k] = 128 KiB

  const int tid = threadIdx.x;
  const int w = tid >> 6;
  const int lane = tid & 63;
  const int wm = (w >> 2) * 128;  // wave row block
  const int wn = (w & 3) * 64;    // wave col block

  // XCD-bijective swizzle (T1): gridDim.x % 8 == 0
  const int nbx = N >> 8;
  const int nwg = nbx * (M >> 8);
  const int bid = blockIdx.x;
  const int swz = (bid & 7) * (nwg >> 3) + (bid >> 3);
  const long bM = (long)(swz / nbx) * 256;
  const long bN = (long)(swz % nbx) * 256;

  // staging per-lane source coords
  const int r0 = tid >> 3;                       // 0..63 (i=1 adds 64 rows)
  const int c8 = (tid & 7) ^ (r0 & 7);
  const bf16* Ag = A + (bM + r0) * (long)K + c8 * 8;
  const bf16* Bg = BT + (bN + r0) * (long)K + c8 * 8;
  const int lslot = w * 512;                     // wave-uniform LDS elem base

  bf16* Am0 = &lds[0][0][0][0];
  bf16* Am1 = &lds[1][0][0][0];
  bf16* Bm0 = &lds[0][1][0][0];
  bf16* Bm1 = &lds[1][1][0][0];

  auto stage = [&](const bf16* g, bf16* lmat, int half, int kt) {
    const bf16* gs = g + (long)half * 128 * K + (long)kt * 64;
    bf16* ls = lmat + half * 8192 + lslot;
    gl_lds16(gs, ls);
    gl_lds16(gs + 64L * K, ls + 4096);
  };

  // fragment read base byte-offsets (t=0 slot); per-t address = base ^ (t*32)
  const int l31 = lane & 31, l7 = lane & 7, hi5 = lane >> 5;
  const int aA = (wm + l31) * 128 + ((hi5 ^ l7) * 16);
  const int aB = (wn + l31) * 128 + ((hi5 ^ l7) * 16);
  lchar* lb8 = (lchar*)&lds[0][0][0][0];

#define PTA(BUF, T) ((lu16*)(lb8 + (((aA) ^ ((T) * 32)) + (BUF) * 65536)))
#define PTB(BUF, T) ((lu16*)(lb8 + (((aB) ^ ((T) * 32)) + 32768 + (BUF) * 65536)))

  floatx16 acc[4][2];
#pragma unroll
  for (int a = 0; a < 4; a++)
#pragma unroll
    for (int b = 0; b < 2; b++)
#pragma unroll
      for (int i = 0; i < 16; i++) acc[a][b][i] = 0.f;

  short8 af[4][2], bf[2][4];

// 4 independent MFMAs: af[0..3][TA] x bf[NB][TB] -> acc[0..3][NB]
#define MMA4(NB, TA, TB) do { \
  acc[0][NB] = __builtin_amdgcn_mfma_f32_32x32x16_bf16(af[0][TA], bf[NB][TB], acc[0][NB], 0, 0, 0); \
  acc[1][NB] = __builtin_amdgcn_mfma_f32_32x32x16_bf16(af[1][TA], bf[NB][TB], acc[1][NB], 0, 0, 0); \
  acc[2][NB] = __builtin_amdgcn_mfma_f32_32x32x16_bf16(af[2][TA], bf[NB][TB], acc[2][NB], 0, 0, 0); \
  acc[3][NB] = __builtin_amdgcn_mfma_f32_32x32x16_bf16(af[3][TA], bf[NB][TB], acc[3][NB], 0, 0, 0); \
} while (0)

// Phase-A issue: af t0 (#1-4), bf t0 (#5-6), af t1 (#7-10), bf t1 (#11-12),
// bf t2 (#13-14), bf t3 (#15-16)
#define ISSUE_PA(BUF) do { \
  lu16 *pa0 = PTA(BUF, 0), *pb0 = PTB(BUF, 0), *pa1 = PTA(BUF, 1), *pb1 = PTB(BUF, 1); \
  lu16 *pb2 = PTB(BUF, 2), *pb3 = PTB(BUF, 3); \
  af[0][0] = ldsro<0>(pa0); af[1][0] = ldsro<4096>(pa0); \
  af[2][0] = ldsro<8192>(pa0); af[3][0] = ldsro<12288>(pa0); \
  bf[0][0] = ldsro<0>(pb0); bf[1][0] = ldsro<4096>(pb0); \
  af[0][1] = ldsro<0>(pa1); af[1][1] = ldsro<4096>(pa1); \
  af[2][1] = ldsro<8192>(pa1); af[3][1] = ldsro<12288>(pa1); \
  bf[0][1] = ldsro<0>(pb1); bf[1][1] = ldsro<4096>(pb1); \
  bf[0][2] = ldsro<0>(pb2); bf[1][2] = ldsro<4096>(pb2); \
  bf[0][3] = ldsro<0>(pb3); bf[1][3] = ldsro<4096>(pb3); \
} while (0)

// Phase-B issue: af t2 (#1-4), af t3 (#5-8)
#define ISSUE_PB(BUF) do { \
  lu16 *pa2 = PTA(BUF, 2), *pa3 = PTA(BUF, 3); \
  af[0][0] = ldsro<0>(pa2); af[1][0] = ldsro<4096>(pa2); \
  af[2][0] = ldsro<8192>(pa2); af[3][0] = ldsro<12288>(pa2); \
  af[0][1] = ldsro<0>(pa3); af[1][1] = ldsro<4096>(pa3); \
  af[2][1] = ldsro<8192>(pa3); af[3][1] = ldsro<12288>(pa3); \
} while (0)

// one K-tile, 2 phases, 1 barrier each.  SA*/SB* staging stmts; VMX at phB end
#define KTILE(BUF, SA1, SA2, SB1, SB2, VMX) do { \
  ISSUE_PA(BUF); SA1; SA2; \
  __builtin_amdgcn_s_setprio(1); \
  WAITLG(11); MMA4(0, 0, 0); \
  WAITLG(10); MMA4(1, 0, 0); \
  WAITLG(5);  MMA4(0, 1, 1); \
  WAITLG(4);  MMA4(1, 1, 1); \
  WAITLG(0); \
  __builtin_amdgcn_s_setprio(0); BAR(); \
  ISSUE_PB(BUF); SB1; SB2; \
  __builtin_amdgcn_s_setprio(1); \
  WAITLG(4); MMA4(0, 0, 2); MMA4(1, 0, 2); \
  WAITLG(0); MMA4(0, 1, 3); MMA4(1, 1, 3); \
  __builtin_amdgcn_s_setprio(0); \
  VMX; BAR(); \
} while (0)

  // prologue: tile0 -> buf0 (8 loads), tile1 B -> buf1 (4 loads); drain tile0
  stage(Ag, Am0, 0, 0); stage(Ag, Am0, 1, 0);
  stage(Bg, Bm0, 0, 0); stage(Bg, Bm0, 1, 0);
  stage(Bg, Bm1, 0, 1); stage(Bg, Bm1, 1, 1);
  VMCNT(4);
  BAR();

  // staging calendar per iteration i (tile 2i in buf0, 2i+1 in buf1):
  //  KT(2i):   phA stages A(2i+1)->buf1; phB stages B(2i+2)->buf0; vmcnt(4)
  //  KT(2i+1): phA stages A(2i+2)->buf0; phB stages B(2i+3)->buf1; vmcnt(4)
  const int NI = K >> 7;
  for (int i = 0; i < NI - 1; ++i) {
    const int k1 = 2 * i + 1, k2 = 2 * i + 2, k3 = 2 * i + 3;
    KTILE(0,
          stage(Ag, Am1, 0, k1), stage(Ag, Am1, 1, k1),
          stage(Bg, Bm0, 0, k2), stage(Bg, Bm0, 1, k2), VMCNT(4));
    KTILE(1,
          stage(Ag, Am0, 0, k2), stage(Ag, Am0, 1, k2),
          stage(Bg, Bm1, 0, k3), stage(Bg, Bm1, 1, k3), VMCNT(4));
  }
  {
    const int kl = 2 * NI - 1;  // last odd tile: only its A halves remain to stage
    KTILE(0,
          stage(Ag, Am1, 0, kl), stage(Ag, Am1, 1, kl),
          (void)0, (void)0, VMCNT(0));
    KTILE(1,
          (void)0, (void)0, (void)0, (void)0, (void)0);
  }

#undef KTILE
#undef ISSUE_PB
#undef ISSUE_PA
#undef MMA4
#undef PTB
#undef PTA

  // C/D layout (32x32): col = lane&31, row = (reg&3) + 8*(reg>>2) + 4*(lane>>5)
#pragma unroll
  for (int mb = 0; mb < 4; ++mb) {
#pragma unroll
    for (int q = 0; q < 4; ++q) {
#pragma unroll
      for (int r2 = 0; r2 < 4; ++r2) {
        long row = bM + wm + mb * 32 + q * 8 + r2 + 4 * hi5;
        OUT_T* crow = C + row * (long)N + bN + wn + l31;
        stf(&crow[0],  acc[mb][0][q * 4 + r2]);
        stf(&crow[32], acc[mb][1][q * 4 + r2]);
      }
    }
  }
}

// ---------- scan ----------
// c = sigmoid(-gate), v = sigmoid(gate) * g(hidden); g(x) = x>=0 ? x+0.5 : sigmoid(x)
__device__ __forceinline__ void cv_compute(float hval, float gval, float& c, float& v) {
  float eg = __expf(gval);
  c = 1.f / (1.f + eg);
  float z = 1.f - c;
  float gx = (hval >= 0.f) ? (hval + 0.5f) : (1.f / (1.f + __expf(-hval)));
  v = z * gx;
}

// pass1: per (b, chunk, e-quad): P = prod c, V = local recurrence from 0 (4 elems/thread)
__global__ void scan_pass1(const bf16* __restrict__ hg, float* __restrict__ P,
                           float* __restrict__ V, int S, int Di, int NN, int nch) {
  int tid = blockIdx.x * blockDim.x + threadIdx.x;  // over B*nch*(Di/4)
  int De = Di >> 2;
  int e = (tid % De) * 4;
  int rest = tid / De;
  int ch = rest % nch;
  int b = rest / nch;
  int CH = S / nch;
  const bf16* ph = hg + ((long)(b * S + ch * CH)) * NN + e;
  float Pv[4] = {1.f, 1.f, 1.f, 1.f}, Vv[4] = {0.f, 0.f, 0.f, 0.f};
  for (int t = 0; t < CH; t++) {
    float hv[4], gv[4];
    ld4(ph, hv);
    ld4(ph + Di, gv);
#pragma unroll
    for (int j = 0; j < 4; j++) {
      float c, v;
      cv_compute(hv[j], gv[j], c, v);
      Pv[j] *= c;
      Vv[j] = fmaf(c, Vv[j], v);
    }
    ph += NN;
  }
  long base = ((long)(b * nch + ch)) * Di + e;
  *(float4*)&P[base] = make_float4(Pv[0], Pv[1], Pv[2], Pv[3]);
  *(float4*)&V[base] = make_float4(Vv[0], Vv[1], Vv[2], Vv[3]);
}

// pass2: scan the chunk summaries, store carry-in per chunk
__global__ void scan_pass2(const float* __restrict__ P, const float* __restrict__ V,
                           float* __restrict__ Hc, int Di, int nch) {
  int tid = blockIdx.x * blockDim.x + threadIdx.x;  // b*Di + e
  int e = tid % Di;
  int b = tid / Di;
  float H = 0.f;
  for (int j = 0; j < nch; j++) {
    long idx = ((long)(b * nch + j)) * Di + e;
    Hc[idx] = H;
    H = fmaf(P[idx], H, V[idx]);
  }
}

// pass3: replay chunk with carry, write h (bf16), 4 elems/thread
__global__ void scan_pass3(const bf16* __restrict__ hg, const float* __restrict__ Hc,
                           bf16* __restrict__ h, int S, int Di, int NN, int nch) {
  int tid = blockIdx.x * blockDim.x + threadIdx.x;  // over B*nch*(Di/4)
  int De = Di >> 2;
  int e = (tid % De) * 4;
  int rest = tid / De;
  int ch = rest % nch;
  int b = rest / nch;
  int CH = S / nch;
  const bf16* ph = hg + ((long)(b * S + ch * CH)) * NN + e;
  bf16* po = h + ((long)(b * S + ch * CH)) * Di + e;
  long base = ((long)(b * nch + ch)) * Di + e;
  float4 hc = *(const float4*)&Hc[base];
  float H[4] = {hc.x, hc.y, hc.z, hc.w};
  for (int t = 0; t < CH; t++) {
    float hv[4], gv[4];
    ld4(ph, hv);
    ld4(ph + Di, gv);
    ushort4 o;
#pragma unroll
    for (int j = 0; j < 4; j++) {
      float c, v;
      cv_compute(hv[j], gv[j], c, v);
      H[j] = fmaf(c, H[j], v);
    }
    o.x = f2bu(H[0]); o.y = f2bu(H[1]); o.z = f2bu(H[2]); o.w = f2bu(H[3]);
    *(ushort4*)po = o;
    ph += NN;
    po += Di;
  }
}

// ---------- launch ----------
extern "C" void kernel_launch(void* const* d_in, const int* in_sizes, int n_in,
                              void* d_out, int out_size, void* d_ws, size_t ws_size,
                              hipStream_t stream) {
  const int B = 4, S = 4096, D = 2048, Di = 3072, NN = 6144;
  const int Mr = B * S;       // 16384
  const int NCH = 64;         // chunks per sequence (chunk length 64)

  const float* x = (const float*)d_in[0];
  const float* w_hg = (const float*)d_in[1];
  const float* w_out = (const float*)d_in[2];
  float* out = (float*)d_out;

  char* wp = (char*)d_ws;
  bf16* x_bf = (bf16*)wp;  wp += (size_t)Mr * D * 2;        // 67.1 MB
  bf16* whgT = (bf16*)wp;  wp += (size_t)NN * D * 2;        // 25.2 MB
  bf16* woutT = (bf16*)wp; wp += (size_t)D * Di * 2;        // 12.6 MB
  bf16* h_bf = (bf16*)wp;  wp += (size_t)Mr * Di * 2;       // 100.7 MB
  bf16* hg = (bf16*)wp;    wp += (size_t)Mr * NN * 2;       // 201.3 MB

  // P/V/Hc alias the front of x_bf: x_bf is dead after gemm1 reads it, and
  // is fully rewritten by cvt before the next iteration's gemm1. P/V/Hc are
  // written by pass1/2 (after gemm1) and dead after pass3 -- no overlap.
  float* P = (float*)x_bf;                                  // 3.15 MB
  float* V = P + (size_t)B * NCH * Di;                      // 3.15 MB
  float* Hc = V + (size_t)B * NCH * Di;                     // 3.15 MB

  // conversions / transposes
  cvt_f32_bf16<<<(int)(((long)Mr * D / 4 + 255) / 256), 256, 0, stream>>>(x, x_bf, (long)Mr * D / 4);
  transpose_f32_to_bf16<<<dim3(NN / 32, D / 32), 256, 0, stream>>>(w_hg, whgT, D, NN);
  transpose_f32_to_bf16<<<dim3(D / 32, Di / 32), 256, 0, stream>>>(w_out, woutT, Di, D);

  const int nwg1 = (NN / 256) * (Mr / 256);  // 24*64 = 1536
  const int nwg2 = (D / 256) * (Mr / 256);   // 8*64  = 512
  int scan_vthreads = B * NCH * (Di / 4);    // 196608

  gemm256<bf16><<<nwg1, 512, 0, stream>>>(x_bf, whgT, hg, Mr, NN, D);
  scan_pass1<<<scan_vthreads / 256, 256, 0, stream>>>(hg, P, V, S, Di, NN, NCH);
  scan_pass2<<<(B * Di) / 256, 256, 0, stream>>>(P, V, Hc, Di, NCH);
  scan_pass3<<<scan_vthreads / 256, 256, 0, stream>>>(hg, Hc, h_bf, S, Di, NN, NCH);

  gemm256<float><<<nwg2, 512, 0, stream>>>(h_bf, woutT, out, Mr, D, Di);
}